// Round 1
// baseline (1447.739 us; speedup 1.0000x reference)
//
#include <hip/hip_runtime.h>
#include <hip/hip_bf16.h>

#define B_    4
#define C_    256
#define H_    128
#define W_    128
#define NW_   256     // number of windows (B*8*8)
#define N_    256     // tokens per window
#define DA_   64
#define MID_  1024
#define SCALE_ 0.125f

typedef __attribute__((ext_vector_type(8))) __bf16 frag8;
typedef __attribute__((ext_vector_type(4))) float  f32x4;

#define MFMA(a, b, c) __builtin_amdgcn_mfma_f32_16x16x32_bf16(a, b, c, 0, 0, 0)

__device__ __forceinline__ unsigned short f2bf(float x) {
    union { float f; unsigned u; } v; v.f = x;
    unsigned r = v.u + 0x7FFFu + ((v.u >> 16) & 1u);
    return (unsigned short)(r >> 16);
}
__device__ __forceinline__ float bf2f(unsigned short h) {
    union { unsigned u; float f; } v; v.u = ((unsigned)h) << 16;
    return v.f;
}
__device__ __forceinline__ frag8 loadf8(const unsigned short* p) {
    return *reinterpret_cast<const frag8*>(p);
}

// ---------------- weight prep: fold scales, cast to bf16 ----------------
__global__ void k_wprep(const float* __restrict__ qw, const float* __restrict__ qs,
                        const float* __restrict__ kw, const float* __restrict__ ks,
                        const float* __restrict__ vgw, const float* __restrict__ vgs,
                        const float* __restrict__ pw, const float* __restrict__ ps,
                        unsigned short* __restrict__ wvg,
                        unsigned short* __restrict__ wqk,
                        unsigned short* __restrict__ wp) {
    int i = blockIdx.x * 256 + threadIdx.x;
    if (i < 2048 * 256) {
        int r = i >> 8;
        wvg[i] = f2bf(vgw[i] * vgs[r]);
        return;
    }
    int j = i - 2048 * 256;
    if (j < 128 * 256) {
        int r = j >> 8, c = j & 255;
        float v = (r < 64) ? qw[r * 256 + c] * qs[r] * SCALE_
                           : kw[(r - 64) * 256 + c] * ks[r - 64];
        wqk[j] = f2bf(v);
        return;
    }
    int m = j - 128 * 256;
    if (m < 256 * 1024) {
        int o = m >> 10;
        wp[m] = f2bf(pw[m] * ps[o]);
    }
}

// ---------------- pack: x[B,C,H,W] -> xfT[win][n][c] bf16 ----------------
__global__ void k_pack(const float* __restrict__ x, unsigned short* __restrict__ xfT) {
    __shared__ unsigned short tile[64][258];
    int wdw = blockIdx.x >> 2, cq = blockIdx.x & 3;
    int b = wdw >> 6, wh = (wdw >> 3) & 7, ww = wdw & 7;
    int tid = threadIdx.x;
    int n = tid;
    int h = wh * 16 + (n >> 4), wc = ww * 16 + (n & 15);
    const float* xb = x + ((long)(b * C_ + cq * 64)) * (H_ * W_) + h * W_ + wc;
    #pragma unroll 4
    for (int cl = 0; cl < 64; ++cl)
        tile[cl][n] = f2bf(xb[cl * H_ * W_]);
    __syncthreads();
    unsigned short* dst = xfT + (long)wdw * (N_ * C_) + cq * 64;
    int cl = tid & 63;
    #pragma unroll 4
    for (int it = 0; it < 64; ++it) {
        int nn = it * 4 + (tid >> 6);
        dst[nn * C_ + cl] = tile[cl][nn];
    }
}

// ---------------- attention: q/k conv + softmax(q^T k) -> attn bf16 ----------------
__global__ __launch_bounds__(256) void k_attn(const unsigned short* __restrict__ xfT,
                                              const unsigned short* __restrict__ wqk,
                                              const float* __restrict__ qb,
                                              const float* __restrict__ kb,
                                              unsigned short* __restrict__ attn) {
    __shared__ __align__(16) unsigned short qT[256][72];
    __shared__ __align__(16) unsigned short kT[256][72];
    int wdw = blockIdx.x;
    int tid = threadIdx.x, w = tid >> 6, l = tid & 63;
    int l16 = l & 15, lg = l >> 4;
    const unsigned short* xw = xfT + (long)wdw * (N_ * C_);

    // stage 1: preact[128 rows][256 n] = Wqk @ xf ; rows 0-63 q, 64-127 k
    f32x4 acc[2][16];
    #pragma unroll
    for (int a = 0; a < 2; ++a)
        #pragma unroll
        for (int c = 0; c < 16; ++c) acc[a][c] = (f32x4){0.f, 0.f, 0.f, 0.f};
    for (int kk = 0; kk < 8; ++kk) {
        int c0 = kk * 32 + lg * 8;
        frag8 af0 = loadf8(wqk + (w * 32 + l16) * 256 + c0);
        frag8 af1 = loadf8(wqk + (w * 32 + 16 + l16) * 256 + c0);
        #pragma unroll
        for (int ct = 0; ct < 16; ++ct) {
            frag8 bf = loadf8(xw + (ct * 16 + l16) * 256 + c0);
            acc[0][ct] = MFMA(af0, bf, acc[0][ct]);
            acc[1][ct] = MFMA(af1, bf, acc[1][ct]);
        }
    }
    // bias + transpose-store to qT[n][da] / kT[m][da]
    #pragma unroll
    for (int rt = 0; rt < 2; ++rt) {
        int rowb = w * 32 + rt * 16 + lg * 4;
        #pragma unroll
        for (int ct = 0; ct < 16; ++ct) {
            int col = ct * 16 + l16;
            ushort4 t;
            float b0 = (rowb < 64) ? qb[rowb + 0] * SCALE_ : kb[rowb - 64 + 0];
            float b1 = (rowb < 64) ? qb[rowb + 1] * SCALE_ : kb[rowb - 64 + 1];
            float b2 = (rowb < 64) ? qb[rowb + 2] * SCALE_ : kb[rowb - 64 + 2];
            float b3 = (rowb < 64) ? qb[rowb + 3] * SCALE_ : kb[rowb - 64 + 3];
            t.x = f2bf(acc[rt][ct][0] + b0);
            t.y = f2bf(acc[rt][ct][1] + b1);
            t.z = f2bf(acc[rt][ct][2] + b2);
            t.w = f2bf(acc[rt][ct][3] + b3);
            unsigned short* dstp = (rowb < 64) ? &qT[col][rowb] : &kT[col][rowb - 64];
            *reinterpret_cast<ushort4*>(dstp) = t;
        }
    }
    __syncthreads();

    // stage 2: logits (64 n-rows per pass), softmax over m, store attn[n][m]
    for (int nb = 0; nb < 4; ++nb) {
        int n0 = nb * 64;
        f32x4 a2[16];
        #pragma unroll
        for (int c = 0; c < 16; ++c) a2[c] = (f32x4){0.f, 0.f, 0.f, 0.f};
        #pragma unroll
        for (int kk = 0; kk < 2; ++kk) {
            int k0 = kk * 32 + lg * 8;
            frag8 af = loadf8(&qT[n0 + w * 16 + l16][k0]);
            #pragma unroll
            for (int ct = 0; ct < 16; ++ct) {
                frag8 bf = loadf8(&kT[ct * 16 + l16][k0]);
                a2[ct] = MFMA(af, bf, a2[ct]);
            }
        }
        #pragma unroll
        for (int r = 0; r < 4; ++r) {
            int n = n0 + w * 16 + lg * 4 + r;
            float mx = -1e30f;
            #pragma unroll
            for (int ct = 0; ct < 16; ++ct) mx = fmaxf(mx, a2[ct][r]);
            #pragma unroll
            for (int d = 1; d < 16; d <<= 1) mx = fmaxf(mx, __shfl_xor(mx, d, 64));
            float p[16], s = 0.f;
            #pragma unroll
            for (int ct = 0; ct < 16; ++ct) { p[ct] = __expf(a2[ct][r] - mx); s += p[ct]; }
            #pragma unroll
            for (int d = 1; d < 16; d <<= 1) s += __shfl_xor(s, d, 64);
            float inv = 1.f / s;
            unsigned short* dst = attn + (long)wdw * (N_ * N_) + n * 256 + l16;
            #pragma unroll
            for (int ct = 0; ct < 16; ++ct) dst[ct * 16] = f2bf(p[ct] * inv);
        }
    }
}

// ---------------- main fused kernel: vg conv -> PV -> gate -> p conv ----------------
__global__ __launch_bounds__(512, 2) void k_main(const unsigned short* __restrict__ xfT,
                                                 const unsigned short* __restrict__ attn,
                                                 const unsigned short* __restrict__ wvg,
                                                 const unsigned short* __restrict__ wp,
                                                 const float* __restrict__ vgb,
                                                 const float* __restrict__ pb,
                                                 float* __restrict__ out) {
    __shared__ __align__(16) unsigned short vlds[64][264];
    __shared__ __align__(16) unsigned short glds[64][264];
    __shared__ __align__(16) unsigned short pvgT[256][72];
    int wdw = blockIdx.x;
    int tid = threadIdx.x, w = tid >> 6, l = tid & 63;
    int l16 = l & 15, lg = l >> 4;
    const unsigned short* xw = xfT + (long)wdw * (N_ * C_);
    const unsigned short* aw = attn + (long)wdw * (N_ * N_);

    f32x4 acc[2][16];   // persistent output accumulator: rows [32w,32w+32) x all 256 n
    #pragma unroll
    for (int a = 0; a < 2; ++a)
        #pragma unroll
        for (int c = 0; c < 16; ++c) acc[a][c] = (f32x4){0.f, 0.f, 0.f, 0.f};

    for (int mt = 0; mt < 16; ++mt) {
        int mid0 = mt * 64;

        // ---- stage A: vg preact rows 0..127 (0-63: v, 64-127: gate), cols n 0..255
        f32x4 accA[16];
        #pragma unroll
        for (int c = 0; c < 16; ++c) accA[c] = (f32x4){0.f, 0.f, 0.f, 0.f};
        int prowA = w * 16 + l16;
        int wrow = (prowA < 64) ? (mid0 + prowA) : (MID_ + mid0 + prowA - 64);
        const unsigned short* wrowp = wvg + wrow * 256;
        for (int kk = 0; kk < 8; ++kk) {
            int c0 = kk * 32 + lg * 8;
            frag8 af = loadf8(wrowp + c0);
            #pragma unroll
            for (int ct = 0; ct < 16; ++ct) {
                frag8 bf = loadf8(xw + (ct * 16 + l16) * 256 + c0);
                accA[ct] = MFMA(af, bf, accA[ct]);
            }
        }
        {   // bias + sigmoid + store to vlds/glds
            int rowb = w * 16 + lg * 4;
            #pragma unroll
            for (int ct = 0; ct < 16; ++ct) {
                int col = ct * 16 + l16;
                #pragma unroll
                for (int r = 0; r < 4; ++r) {
                    int row = rowb + r;
                    float bias = (row < 64) ? vgb[mid0 + row] : vgb[MID_ + mid0 + row - 64];
                    float sg = 1.f / (1.f + __expf(-(accA[ct][r] + bias)));
                    if (row < 64) vlds[row][col] = f2bf(sg);
                    else          glds[row - 64][col] = f2bf(sg);
                }
            }
        }
        __syncthreads();   // (1) v/gate ready; prev-iter pvgT readers done

        // ---- stage B: pv[64 mid][256 n] = v @ attn^T, gated, -> pvgT[n][mid]
        int rt = w & 3, ch = w >> 2;
        f32x4 accB[8];
        #pragma unroll
        for (int c = 0; c < 8; ++c) accB[c] = (f32x4){0.f, 0.f, 0.f, 0.f};
        for (int mm = 0; mm < 8; ++mm) {
            int m0 = mm * 32 + lg * 8;
            frag8 af = loadf8(&vlds[rt * 16 + l16][m0]);
            #pragma unroll
            for (int ci = 0; ci < 8; ++ci) {
                int n = (ch * 8 + ci) * 16 + l16;
                frag8 bf = loadf8(aw + n * 256 + m0);
                accB[ci] = MFMA(af, bf, accB[ci]);
            }
        }
        {
            int midb = rt * 16 + lg * 4;
            #pragma unroll
            for (int ci = 0; ci < 8; ++ci) {
                int n = (ch * 8 + ci) * 16 + l16;
                ushort4 t;
                t.x = f2bf(accB[ci][0] * bf2f(glds[midb + 0][n]));
                t.y = f2bf(accB[ci][1] * bf2f(glds[midb + 1][n]));
                t.z = f2bf(accB[ci][2] * bf2f(glds[midb + 2][n]));
                t.w = f2bf(accB[ci][3] * bf2f(glds[midb + 3][n]));
                *reinterpret_cast<ushort4*>(&pvgT[n][midb]) = t;
            }
        }
        __syncthreads();   // (2) pvgT ready

        // ---- stage C: acc += wp[:, mid0:mid0+64] @ pvg
        const unsigned short* wpp = wp + mid0;
        #pragma unroll
        for (int kk = 0; kk < 2; ++kk) {
            int k0 = kk * 32 + lg * 8;
            frag8 a0 = loadf8(wpp + (w * 32 + l16) * 1024 + k0);
            frag8 a1 = loadf8(wpp + (w * 32 + 16 + l16) * 1024 + k0);
            #pragma unroll
            for (int ct = 0; ct < 16; ++ct) {
                frag8 bf = loadf8(&pvgT[ct * 16 + l16][k0]);
                acc[0][ct] = MFMA(a0, bf, acc[0][ct]);
                acc[1][ct] = MFMA(a1, bf, acc[1][ct]);
            }
        }
        // no barrier needed here: next writes to vlds/pvgT are separated by (1)/(2)
    }

    // ---- epilogue: bias + window-reverse store
    int b = wdw >> 6, wh = (wdw >> 3) & 7, ww = wdw & 7;
    #pragma unroll
    for (int rt2 = 0; rt2 < 2; ++rt2) {
        #pragma unroll
        for (int ct = 0; ct < 16; ++ct) {
            int h = wh * 16 + ct, wc = ww * 16 + l16;
            #pragma unroll
            for (int r = 0; r < 4; ++r) {
                int o = w * 32 + rt2 * 16 + lg * 4 + r;
                out[(((long)(b * C_ + o)) * H_ + h) * W_ + wc] = acc[rt2][ct][r] + pb[o];
            }
        }
    }
}

extern "C" void kernel_launch(void* const* d_in, const int* in_sizes, int n_in,
                              void* d_out, int out_size, void* d_ws, size_t ws_size,
                              hipStream_t stream) {
    const float* x    = (const float*)d_in[0];
    const float* q_w  = (const float*)d_in[1];
    const float* q_s  = (const float*)d_in[2];
    const float* q_b  = (const float*)d_in[3];
    const float* k_w  = (const float*)d_in[4];
    const float* k_s  = (const float*)d_in[5];
    const float* k_b  = (const float*)d_in[6];
    const float* vg_w = (const float*)d_in[7];
    const float* vg_s = (const float*)d_in[8];
    const float* vg_b = (const float*)d_in[9];
    const float* p_w  = (const float*)d_in[10];
    const float* p_s  = (const float*)d_in[11];
    const float* p_b  = (const float*)d_in[12];

    // ws layout (bf16 as ushort)
    unsigned short* xfT  = (unsigned short*)d_ws;                    // 256*256*256
    unsigned short* attn = xfT + (size_t)NW_ * N_ * C_;              // 256*256*256
    unsigned short* wvg  = attn + (size_t)NW_ * N_ * N_;             // 2048*256
    unsigned short* wqk  = wvg + 2048 * 256;                         // 128*256
    unsigned short* wp   = wqk + 128 * 256;                          // 256*1024
    size_t need = ((size_t)NW_ * N_ * C_ + (size_t)NW_ * N_ * N_ +
                   2048 * 256 + 128 * 256 + 256 * 1024) * sizeof(unsigned short);
    if (ws_size < need) return;  // fail loudly via validation rather than corrupt

    k_wprep<<<3200, 256, 0, stream>>>(q_w, q_s, k_w, k_s, vg_w, vg_s, p_w, p_s,
                                      wvg, wqk, wp);
    k_pack<<<1024, 256, 0, stream>>>(x, xfT);
    k_attn<<<NW_, 256, 0, stream>>>(xfT, wqk, q_b, k_b, attn);
    k_main<<<NW_, 512, 0, stream>>>(xfT, attn, wvg, wp, vg_b, p_b, (float*)d_out);
}

// Round 2
// 723.141 us; speedup vs baseline: 2.0020x; 2.0020x over previous
//
#include <hip/hip_runtime.h>
#include <hip/hip_bf16.h>

#define B_    4
#define C_    256
#define H_    128
#define W_    128
#define NW_   256     // number of windows (B*8*8)
#define N_    256     // tokens per window
#define DA_   64
#define MID_  1024
#define SCALE_ 0.125f

typedef __attribute__((ext_vector_type(8))) __bf16 frag8;
typedef __attribute__((ext_vector_type(4))) float  f32x4;

#define MFMA(a, b, c) __builtin_amdgcn_mfma_f32_16x16x32_bf16(a, b, c, 0, 0, 0)

__device__ __forceinline__ unsigned short f2bf(float x) {
    union { float f; unsigned u; } v; v.f = x;
    unsigned r = v.u + 0x7FFFu + ((v.u >> 16) & 1u);
    return (unsigned short)(r >> 16);
}
__device__ __forceinline__ float bf2f(unsigned short h) {
    union { unsigned u; float f; } v; v.u = ((unsigned)h) << 16;
    return v.f;
}
__device__ __forceinline__ frag8 loadf8(const unsigned short* p) {
    return *reinterpret_cast<const frag8*>(p);
}

// ---------------- weight prep: fold scales, cast to bf16 ----------------
__global__ void k_wprep(const float* __restrict__ qw, const float* __restrict__ qs,
                        const float* __restrict__ kw, const float* __restrict__ ks,
                        const float* __restrict__ vgw, const float* __restrict__ vgs,
                        const float* __restrict__ pw, const float* __restrict__ ps,
                        unsigned short* __restrict__ wvg,
                        unsigned short* __restrict__ wqk,
                        unsigned short* __restrict__ wp) {
    int i = blockIdx.x * 256 + threadIdx.x;
    if (i < 2048 * 256) {
        int r = i >> 8;
        wvg[i] = f2bf(vgw[i] * vgs[r]);
        return;
    }
    int j = i - 2048 * 256;
    if (j < 128 * 256) {
        int r = j >> 8, c = j & 255;
        float v = (r < 64) ? qw[r * 256 + c] * qs[r] * SCALE_
                           : kw[(r - 64) * 256 + c] * ks[r - 64];
        wqk[j] = f2bf(v);
        return;
    }
    int m = j - 128 * 256;
    if (m < 256 * 1024) {
        int o = m >> 10;
        wp[m] = f2bf(pw[m] * ps[o]);
    }
}

// ---------------- pack: x[B,C,H,W] -> xfT[win][n][c] bf16 ----------------
__global__ void k_pack(const float* __restrict__ x, unsigned short* __restrict__ xfT) {
    __shared__ unsigned short tile[64][258];
    int wdw = blockIdx.x >> 2, cq = blockIdx.x & 3;
    int b = wdw >> 6, wh = (wdw >> 3) & 7, ww = wdw & 7;
    int tid = threadIdx.x;
    int n = tid;
    int h = wh * 16 + (n >> 4), wc = ww * 16 + (n & 15);
    const float* xb = x + ((long)(b * C_ + cq * 64)) * (H_ * W_) + h * W_ + wc;
    #pragma unroll 4
    for (int cl = 0; cl < 64; ++cl)
        tile[cl][n] = f2bf(xb[cl * H_ * W_]);
    __syncthreads();
    unsigned short* dst = xfT + (long)wdw * (N_ * C_) + cq * 64;
    int cl = tid & 63;
    #pragma unroll 4
    for (int it = 0; it < 64; ++it) {
        int nn = it * 4 + (tid >> 6);
        dst[nn * C_ + cl] = tile[cl][nn];
    }
}

// ---------------- attention: q/k conv + softmax(q^T k) -> attn bf16 ----------------
__global__ __launch_bounds__(256) void k_attn(const unsigned short* __restrict__ xfT,
                                              const unsigned short* __restrict__ wqk,
                                              const float* __restrict__ qb,
                                              const float* __restrict__ kb,
                                              unsigned short* __restrict__ attn) {
    __shared__ __align__(16) unsigned short qT[256][72];
    __shared__ __align__(16) unsigned short kT[256][72];
    int wdw = blockIdx.x;
    int tid = threadIdx.x, w = tid >> 6, l = tid & 63;
    int l16 = l & 15, lg = l >> 4;
    const unsigned short* xw = xfT + (long)wdw * (N_ * C_);

    // stage 1: preact[128 rows][256 n] = Wqk @ xf ; n-split: wave owns 64 cols
    f32x4 acc[8][4];
    #pragma unroll
    for (int a = 0; a < 8; ++a)
        #pragma unroll
        for (int c = 0; c < 4; ++c) acc[a][c] = (f32x4){0.f, 0.f, 0.f, 0.f};
    for (int kk = 0; kk < 8; ++kk) {
        int c0 = kk * 32 + lg * 8;
        frag8 bfr[4];
        #pragma unroll
        for (int ct = 0; ct < 4; ++ct)
            bfr[ct] = loadf8(xw + (64 * w + ct * 16 + l16) * 256 + c0);
        #pragma unroll
        for (int rt = 0; rt < 8; ++rt) {
            frag8 af = loadf8(wqk + (rt * 16 + l16) * 256 + c0);
            #pragma unroll
            for (int ct = 0; ct < 4; ++ct)
                acc[rt][ct] = MFMA(af, bfr[ct], acc[rt][ct]);
        }
    }
    // bias + transpose-store to qT[n][da] / kT[m][da]
    #pragma unroll
    for (int rt = 0; rt < 8; ++rt) {
        int rowb = rt * 16 + lg * 4;
        bool isq = rt < 4;
        float b0 = isq ? qb[rowb + 0] * SCALE_ : kb[rowb - 64 + 0];
        float b1 = isq ? qb[rowb + 1] * SCALE_ : kb[rowb - 64 + 1];
        float b2 = isq ? qb[rowb + 2] * SCALE_ : kb[rowb - 64 + 2];
        float b3 = isq ? qb[rowb + 3] * SCALE_ : kb[rowb - 64 + 3];
        #pragma unroll
        for (int ct = 0; ct < 4; ++ct) {
            int col = 64 * w + ct * 16 + l16;
            ushort4 t;
            t.x = f2bf(acc[rt][ct][0] + b0);
            t.y = f2bf(acc[rt][ct][1] + b1);
            t.z = f2bf(acc[rt][ct][2] + b2);
            t.w = f2bf(acc[rt][ct][3] + b3);
            unsigned short* dstp = isq ? &qT[col][rowb] : &kT[col][rowb - 64];
            *reinterpret_cast<ushort4*>(dstp) = t;
        }
    }
    __syncthreads();

    // stage 2: logits (64 n-rows per pass), softmax over m, store attn[n][m]
    for (int nb = 0; nb < 4; ++nb) {
        int n0 = nb * 64;
        f32x4 a2[16];
        #pragma unroll
        for (int c = 0; c < 16; ++c) a2[c] = (f32x4){0.f, 0.f, 0.f, 0.f};
        #pragma unroll
        for (int kk = 0; kk < 2; ++kk) {
            int k0 = kk * 32 + lg * 8;
            frag8 af = loadf8(&qT[n0 + w * 16 + l16][k0]);
            #pragma unroll
            for (int ct = 0; ct < 16; ++ct) {
                frag8 bf = loadf8(&kT[ct * 16 + l16][k0]);
                a2[ct] = MFMA(af, bf, a2[ct]);
            }
        }
        #pragma unroll
        for (int r = 0; r < 4; ++r) {
            int n = n0 + w * 16 + lg * 4 + r;
            float mx = -1e30f;
            #pragma unroll
            for (int ct = 0; ct < 16; ++ct) mx = fmaxf(mx, a2[ct][r]);
            #pragma unroll
            for (int d = 1; d < 16; d <<= 1) mx = fmaxf(mx, __shfl_xor(mx, d, 64));
            float p[16], s = 0.f;
            #pragma unroll
            for (int ct = 0; ct < 16; ++ct) { p[ct] = __expf(a2[ct][r] - mx); s += p[ct]; }
            #pragma unroll
            for (int d = 1; d < 16; d <<= 1) s += __shfl_xor(s, d, 64);
            float inv = __builtin_amdgcn_rcpf(s);
            unsigned short* dst = attn + (long)wdw * (N_ * N_) + n * 256 + l16;
            #pragma unroll
            for (int ct = 0; ct < 16; ++ct) dst[ct * 16] = f2bf(p[ct] * inv);
        }
    }
}

// ---------------- main fused kernel: vg conv -> PV -> gate -> p conv ----------------
// n-split: wave w owns n-cols [32w, 32w+32). Per mid-tile the block reads xf and
// attn exactly once; redundant reads hit the L2-resident shared weights instead.
__global__ __launch_bounds__(512, 2) void k_main(const unsigned short* __restrict__ xfT,
                                                 const unsigned short* __restrict__ attn,
                                                 const unsigned short* __restrict__ wvg,
                                                 const unsigned short* __restrict__ wp,
                                                 const float* __restrict__ vgb,
                                                 const float* __restrict__ pb,
                                                 float* __restrict__ out) {
    __shared__ __align__(16) unsigned short vlds[64][264];
    __shared__ __align__(16) unsigned short glds[64][264];
    __shared__ __align__(16) unsigned short pvgT[256][72];
    __shared__ float vgb_s[2048];
    __shared__ float pb_s[256];
    int wdw = blockIdx.x;
    int tid = threadIdx.x, w = tid >> 6, l = tid & 63;
    int l16 = l & 15, lg = l >> 4;
    int nb = 32 * w;                       // wave's n-column base
    const unsigned short* xw = xfT + (long)wdw * (N_ * C_);
    const unsigned short* aw = attn + (long)wdw * (N_ * N_);

    {   // stage biases to LDS (2048 + 256 floats)
        float4 v = reinterpret_cast<const float4*>(vgb)[tid];
        reinterpret_cast<float4*>(vgb_s)[tid] = v;
        if (tid < 256) pb_s[tid] = pb[tid];
    }

    f32x4 acc3[16][2];   // persistent: [c=256 rows] x [wave's 32 n-cols]
    #pragma unroll
    for (int a = 0; a < 16; ++a)
        #pragma unroll
        for (int c = 0; c < 2; ++c) acc3[a][c] = (f32x4){0.f, 0.f, 0.f, 0.f};

    __syncthreads();

    for (int mt = 0; mt < 16; ++mt) {
        int mid0 = mt * 64;

        // ---- stage A: vg preact slab [128 rows][wave's 32 n]
        f32x4 accA[8][2];
        #pragma unroll
        for (int a = 0; a < 8; ++a) {
            accA[a][0] = (f32x4){0.f, 0.f, 0.f, 0.f};
            accA[a][1] = (f32x4){0.f, 0.f, 0.f, 0.f};
        }
        for (int kk = 0; kk < 8; ++kk) {
            int c0 = kk * 32 + lg * 8;
            frag8 b0 = loadf8(xw + (nb + l16) * 256 + c0);
            frag8 b1 = loadf8(xw + (nb + 16 + l16) * 256 + c0);
            #pragma unroll
            for (int rt = 0; rt < 8; ++rt) {
                int s = rt * 16 + l16;
                int row = (rt < 4) ? (mid0 + s) : (MID_ + mid0 + s - 64);
                frag8 af = loadf8(wvg + row * 256 + c0);
                accA[rt][0] = MFMA(af, b0, accA[rt][0]);
                accA[rt][1] = MFMA(af, b1, accA[rt][1]);
            }
        }
        // bias + sigmoid + store to vlds/glds
        #pragma unroll
        for (int rt = 0; rt < 8; ++rt) {
            #pragma unroll
            for (int ct = 0; ct < 2; ++ct) {
                int col = nb + ct * 16 + l16;
                #pragma unroll
                for (int r = 0; r < 4; ++r) {
                    int s = rt * 16 + lg * 4 + r;
                    float bias = (rt < 4) ? vgb_s[mid0 + s] : vgb_s[MID_ + mid0 + s - 64];
                    float t = accA[rt][ct][r] + bias;
                    float sg = __builtin_amdgcn_rcpf(1.f + __expf(-t));
                    if (rt < 4) vlds[s][col] = f2bf(sg);
                    else        glds[s - 64][col] = f2bf(sg);
                }
            }
        }
        __syncthreads();   // (1) v/gate ready; prev pvgT readers done

        // ---- stage B: pv slab [64 mid][wave's 32 n] = v @ attn^T, gated -> pvgT
        f32x4 acc2[4][2];
        #pragma unroll
        for (int a = 0; a < 4; ++a) {
            acc2[a][0] = (f32x4){0.f, 0.f, 0.f, 0.f};
            acc2[a][1] = (f32x4){0.f, 0.f, 0.f, 0.f};
        }
        for (int kk = 0; kk < 8; ++kk) {
            int m0 = kk * 32 + lg * 8;
            frag8 b0 = loadf8(aw + (nb + l16) * 256 + m0);
            frag8 b1 = loadf8(aw + (nb + 16 + l16) * 256 + m0);
            #pragma unroll
            for (int rt = 0; rt < 4; ++rt) {
                frag8 av = loadf8(&vlds[rt * 16 + l16][m0]);
                acc2[rt][0] = MFMA(av, b0, acc2[rt][0]);
                acc2[rt][1] = MFMA(av, b1, acc2[rt][1]);
            }
        }
        {   // gate multiply + transpose store pvgT[n][mid]
            #pragma unroll
            for (int rt = 0; rt < 4; ++rt) {
                int midb = rt * 16 + lg * 4;
                #pragma unroll
                for (int ct = 0; ct < 2; ++ct) {
                    int n = nb + ct * 16 + l16;
                    ushort4 t;
                    t.x = f2bf(acc2[rt][ct][0] * bf2f(glds[midb + 0][n]));
                    t.y = f2bf(acc2[rt][ct][1] * bf2f(glds[midb + 1][n]));
                    t.z = f2bf(acc2[rt][ct][2] * bf2f(glds[midb + 2][n]));
                    t.w = f2bf(acc2[rt][ct][3] * bf2f(glds[midb + 3][n]));
                    *reinterpret_cast<ushort4*>(&pvgT[n][midb]) = t;
                }
            }
        }
        __syncthreads();   // (2) pvgT ready

        // ---- stage C: acc3 += wp[:, mid0:mid0+64] @ pvg
        #pragma unroll
        for (int kk2 = 0; kk2 < 2; ++kk2) {
            int k0 = kk2 * 32 + lg * 8;
            frag8 b0 = loadf8(&pvgT[nb + l16][k0]);
            frag8 b1 = loadf8(&pvgT[nb + 16 + l16][k0]);
            #pragma unroll
            for (int rt = 0; rt < 16; ++rt) {
                frag8 ap = loadf8(wp + (rt * 16 + l16) * 1024 + mid0 + k0);
                acc3[rt][0] = MFMA(ap, b0, acc3[rt][0]);
                acc3[rt][1] = MFMA(ap, b1, acc3[rt][1]);
            }
        }
        // no barrier: next stage-A writes (vlds/glds) don't touch pvgT; barrier (1)
        // separates stage-C pvgT reads from next stage-B pvgT writes.
    }

    // ---- epilogue: bias + window-reverse store
    int b = wdw >> 6, wh = (wdw >> 3) & 7, ww = wdw & 7;
    #pragma unroll
    for (int rt = 0; rt < 16; ++rt) {
        #pragma unroll
        for (int ct = 0; ct < 2; ++ct) {
            int h = wh * 16 + 2 * w + ct;
            int wc = ww * 16 + l16;
            #pragma unroll
            for (int r = 0; r < 4; ++r) {
                int c = rt * 16 + lg * 4 + r;
                out[(((long)(b * C_ + c)) * H_ + h) * W_ + wc] = acc3[rt][ct][r] + pb_s[c];
            }
        }
    }
}

extern "C" void kernel_launch(void* const* d_in, const int* in_sizes, int n_in,
                              void* d_out, int out_size, void* d_ws, size_t ws_size,
                              hipStream_t stream) {
    const float* x    = (const float*)d_in[0];
    const float* q_w  = (const float*)d_in[1];
    const float* q_s  = (const float*)d_in[2];
    const float* q_b  = (const float*)d_in[3];
    const float* k_w  = (const float*)d_in[4];
    const float* k_s  = (const float*)d_in[5];
    const float* k_b  = (const float*)d_in[6];
    const float* vg_w = (const float*)d_in[7];
    const float* vg_s = (const float*)d_in[8];
    const float* vg_b = (const float*)d_in[9];
    const float* p_w  = (const float*)d_in[10];
    const float* p_s  = (const float*)d_in[11];
    const float* p_b  = (const float*)d_in[12];

    // ws layout (bf16 as ushort)
    unsigned short* xfT  = (unsigned short*)d_ws;                    // 256*256*256
    unsigned short* attn = xfT + (size_t)NW_ * N_ * C_;              // 256*256*256
    unsigned short* wvg  = attn + (size_t)NW_ * N_ * N_;             // 2048*256
    unsigned short* wqk  = wvg + 2048 * 256;                         // 128*256
    unsigned short* wp   = wqk + 128 * 256;                          // 256*1024
    size_t need = ((size_t)NW_ * N_ * C_ + (size_t)NW_ * N_ * N_ +
                   2048 * 256 + 128 * 256 + 256 * 1024) * sizeof(unsigned short);
    if (ws_size < need) return;

    k_wprep<<<3200, 256, 0, stream>>>(q_w, q_s, k_w, k_s, vg_w, vg_s, p_w, p_s,
                                      wvg, wqk, wp);
    k_pack<<<1024, 256, 0, stream>>>(x, xfT);
    k_attn<<<NW_, 256, 0, stream>>>(xfT, wqk, q_b, k_b, attn);
    k_main<<<NW_, 512, 0, stream>>>(xfT, attn, wvg, wp, vg_b, p_b, (float*)d_out);
}